// Round 8
// baseline (471.097 us; speedup 1.0000x reference)
//
#include <hip/hip_runtime.h>

#define TT 64
#define CC 384
#define NH 6
#define HID 1536
#define LDX 392   // attn: padded cols for 64x384 bf16 tiles
#define LDH 72    // attn head tiles (144B stride)

typedef __bf16 bf16x8 __attribute__((ext_vector_type(8)));
typedef float f32x4 __attribute__((ext_vector_type(4)));
typedef unsigned short us8 __attribute__((ext_vector_type(8)));

#define MFMA(a, b, c) __builtin_amdgcn_mfma_f32_16x16x32_bf16(a, b, c, 0, 0, 0)
#define WAITVM(N) asm volatile("s_waitcnt vmcnt(" #N ")" ::: "memory")

static __device__ __forceinline__ unsigned short f2bf(float f) {
  unsigned u = __builtin_bit_cast(unsigned, f);
  u += 0x7FFFu + ((u >> 16) & 1u);
  return (unsigned short)(u >> 16);
}
static __device__ __forceinline__ float bf2f(unsigned short h) {
  unsigned u = ((unsigned)h) << 16;
  return __builtin_bit_cast(float, u);
}
static __device__ __forceinline__ bf16x8 ld8(const unsigned short* p) {
  return __builtin_bit_cast(bf16x8, *reinterpret_cast<const us8*>(p));
}
// async global->LDS, 16B per lane; lds dest = wave-uniform base + lane*16
static __device__ __forceinline__ void glds16(const unsigned short* g, unsigned short* l) {
  __builtin_amdgcn_global_load_lds(
      (const __attribute__((address_space(1))) void*)g,
      (__attribute__((address_space(3))) void*)l, 16, 0, 0);
}

// ---- weight prep: fp32 -> bf16, transposed to [n][k] for MFMA B-frags ----
__global__ void prep_w(const float* __restrict__ Wq, const float* __restrict__ Wk,
                       const float* __restrict__ Wv, const float* __restrict__ Wo,
                       const float* __restrict__ W1, const float* __restrict__ W2,
                       unsigned short* __restrict__ ws) {
  const int T0 = 1152 * 384;            // Wqkv [h*192+j][k]
  const int T1 = T0 + 384 * 384;        // WoT  [n][k]
  const int T2 = T1 + 1536 * 384;       // W1T  [n][k]
  const int T3 = T2 + 384 * 1536;       // W2T  [n][k]
  for (int i = blockIdx.x * blockDim.x + threadIdx.x; i < T3; i += gridDim.x * blockDim.x) {
    float v;
    if (i < T0) {
      int n = i / 384, k = i % 384;
      int hh = n / 192, j = n % 192;
      const float* W = (j < 64) ? Wq : (j < 128) ? Wk : Wv;
      int d = (j < 64) ? j : (j < 128) ? j - 64 : j - 128;
      v = W[((size_t)hh * 384 + k) * 64 + d];
    } else if (i < T1) {
      int i2 = i - T0; int n = i2 / 384, k = i2 % 384;
      v = Wo[(size_t)k * 384 + n];
    } else if (i < T2) {
      int i2 = i - T1; int n = i2 / 384, k = i2 % 384;
      v = W1[(size_t)k * 1536 + n];
    } else {
      int i2 = i - T2; int n = i2 / 1536, k = i2 % 1536;
      v = W2[(size_t)k * 384 + n];
    }
    ws[i] = f2bf(v);
  }
}

// ---- kernel A: LN1 + attention + per-head proj accumulation + residual -> x2 (=d_out, fp32)
__global__ __launch_bounds__(256, 2)
void attn_fwd(const float* __restrict__ x,
              const float* __restrict__ ln1g, const float* __restrict__ ln1b,
              const float* __restrict__ bo,
              const unsigned short* __restrict__ Wqkv,
              const unsigned short* __restrict__ WoT,
              float* __restrict__ x2) {
  __shared__ unsigned short sXN[TT * LDX];       // xn1 (bf16)
  __shared__ unsigned short sHEAD[3 * TT * LDH]; // q | k (later att_h) | vT
  unsigned short* sQ = sHEAD;                    // q [t][d]; later P [t][s]
  unsigned short* sK = sHEAD + TT * LDH;         // k [s][d]; later att_h [t][d]
  unsigned short* sV = sHEAD + 2 * TT * LDH;     // vT [d][s]

  const int b = blockIdx.x;
  const int tid = threadIdx.x;
  const int wv = tid >> 6;
  const int ln = tid & 63;
  const int l16 = ln & 15;
  const int lg = ln >> 4;
  const float* xb = x + (size_t)b * TT * CC;
  const f32x4 Z4 = {0.f, 0.f, 0.f, 0.f};

  // ---------- LN1 ----------
#pragma unroll 1
  for (int r = wv * 16; r < wv * 16 + 16; ++r) {
    float v[6], s = 0.f, sq = 0.f;
#pragma unroll
    for (int j = 0; j < 6; ++j) { v[j] = xb[r * CC + ln + 64 * j]; s += v[j]; sq += v[j] * v[j]; }
#pragma unroll
    for (int off = 32; off; off >>= 1) { s += __shfl_xor(s, off); sq += __shfl_xor(sq, off); }
    float mu = s * (1.f / CC);
    float rs = rsqrtf(sq * (1.f / CC) - mu * mu + 1e-5f);
#pragma unroll
    for (int j = 0; j < 6; ++j) {
      int c = ln + 64 * j;
      sXN[r * LDX + c] = f2bf((v[j] - mu) * rs * ln1g[c] + ln1b[c]);
    }
  }
  __syncthreads();

  f32x4 pacc[4][6];
#pragma unroll
  for (int m = 0; m < 4; ++m)
#pragma unroll
    for (int c = 0; c < 6; ++c) pacc[m][c] = Z4;

  const unsigned short* prow[6];
#pragma unroll
  for (int c = 0; c < 6; ++c)
    prow[c] = WoT + (size_t)(wv * 96 + c * 16 + l16) * CC + 8 * lg;

#pragma unroll 1
  for (int h = 0; h < NH; ++h) {
    const unsigned short* wrow[3];
#pragma unroll
    for (int c = 0; c < 3; ++c)
      wrow[c] = Wqkv + (size_t)(h * 192 + wv * 48 + c * 16 + l16) * CC + 8 * lg;

    f32x4 qacc[4][3];
#pragma unroll
    for (int m = 0; m < 4; ++m)
#pragma unroll
      for (int c = 0; c < 3; ++c) qacc[m][c] = Z4;

    // depth-2 B prefetch pipeline
    bf16x8 bpre[2][3];
#pragma unroll
    for (int c = 0; c < 3; ++c) bpre[0][c] = ld8(wrow[c] + 0);
#pragma unroll
    for (int c = 0; c < 3; ++c) bpre[1][c] = ld8(wrow[c] + 32);
#pragma unroll
    for (int kk = 0; kk < CC; kk += 32) {
      const int slot = (kk >> 5) & 1;
      bf16x8 bcur[3];
#pragma unroll
      for (int c = 0; c < 3; ++c) bcur[c] = bpre[slot][c];
      if (kk + 64 < CC) {
#pragma unroll
        for (int c = 0; c < 3; ++c) bpre[slot][c] = ld8(wrow[c] + kk + 64);
      }
      bf16x8 a[4];
#pragma unroll
      for (int m = 0; m < 4; ++m)
        a[m] = ld8(&sXN[(m * 16 + l16) * LDX + kk + 8 * lg]);
      __builtin_amdgcn_s_setprio(1);
#pragma unroll
      for (int c = 0; c < 3; ++c)
#pragma unroll
        for (int m = 0; m < 4; ++m) qacc[m][c] = MFMA(a[m], bcur[c], qacc[m][c]);
      __builtin_amdgcn_s_setprio(0);
    }
    __syncthreads();  // B1
    // scatter: q [t][d], k [s][d], vT [d][s]
#pragma unroll
    for (int m = 0; m < 4; ++m)
#pragma unroll
      for (int c = 0; c < 3; ++c) {
        int n = wv * 48 + c * 16 + l16;
#pragma unroll
        for (int rg = 0; rg < 4; ++rg) {
          int t = m * 16 + lg * 4 + rg;
          unsigned short bv = f2bf(qacc[m][c][rg]);
          if (n < 64) sQ[t * LDH + n] = bv;
          else if (n < 128) sK[t * LDH + (n - 64)] = bv;
          else sV[(n - 128) * LDH + t] = bv;
        }
      }
    __syncthreads();  // B2

    // ----- S = q.kT
    f32x4 sacc[4];
#pragma unroll
    for (int c = 0; c < 4; ++c) sacc[c] = Z4;
#pragma unroll
    for (int kk = 0; kk < 64; kk += 32) {
      bf16x8 a = ld8(&sQ[(wv * 16 + l16) * LDH + kk + 8 * lg]);
#pragma unroll
      for (int c = 0; c < 4; ++c) {
        bf16x8 bb = ld8(&sK[(c * 16 + l16) * LDH + kk + 8 * lg]);
        sacc[c] = MFMA(a, bb, sacc[c]);
      }
    }
    // causal softmax
#pragma unroll
    for (int rg = 0; rg < 4; ++rg) {
      int row = wv * 16 + lg * 4 + rg;
      float e[4], mx = -1e30f;
#pragma unroll
      for (int c = 0; c < 4; ++c) {
        int col = c * 16 + l16;
        float vv = sacc[c][rg] * 0.125f;
        e[c] = (col <= row) ? vv : -1e30f;
        mx = fmaxf(mx, e[c]);
      }
#pragma unroll
      for (int off = 8; off; off >>= 1) mx = fmaxf(mx, __shfl_xor(mx, off));
      float sum = 0.f;
#pragma unroll
      for (int c = 0; c < 4; ++c) {
        int col = c * 16 + l16;
        e[c] = (col <= row) ? __expf(e[c] - mx) : 0.f;
        sum += e[c];
      }
#pragma unroll
      for (int off = 8; off; off >>= 1) sum += __shfl_xor(sum, off);
      float inv = 1.f / sum;
#pragma unroll
      for (int c = 0; c < 4; ++c)
        sQ[row * LDH + c * 16 + l16] = f2bf(e[c] * inv);
    }

    // Preload ALL Wo B-frags for this head (latency hides under PV)
    bf16x8 pb[2][6];
#pragma unroll
    for (int s2 = 0; s2 < 2; ++s2)
#pragma unroll
      for (int c = 0; c < 6; ++c)
        pb[s2][c] = ld8(prow[c] + h * 64 + 32 * s2);

    // ----- out_h = P @ V
    f32x4 oacc[4];
#pragma unroll
    for (int c = 0; c < 4; ++c) oacc[c] = Z4;
#pragma unroll
    for (int kk = 0; kk < 64; kk += 32) {
      bf16x8 a = ld8(&sQ[(wv * 16 + l16) * LDH + kk + 8 * lg]);
#pragma unroll
      for (int c = 0; c < 4; ++c) {
        bf16x8 bb = ld8(&sV[(c * 16 + l16) * LDH + kk + 8 * lg]);
        oacc[c] = MFMA(a, bb, oacc[c]);
      }
    }
    __syncthreads();  // B3
#pragma unroll
    for (int c = 0; c < 4; ++c)
#pragma unroll
      for (int rg = 0; rg < 4; ++rg) {
        int t = wv * 16 + lg * 4 + rg;
        sK[t * LDH + c * 16 + l16] = f2bf(oacc[c][rg]);
      }
    __syncthreads();  // B4

    // ----- proj accumulate (B in regs)
    __builtin_amdgcn_s_setprio(1);
#pragma unroll
    for (int kk = 0; kk < 64; kk += 32) {
      const int slot = kk >> 5;
      bf16x8 a[4];
#pragma unroll
      for (int m = 0; m < 4; ++m)
        a[m] = ld8(&sK[(m * 16 + l16) * LDH + kk + 8 * lg]);
#pragma unroll
      for (int c = 0; c < 6; ++c)
#pragma unroll
        for (int m = 0; m < 4; ++m) pacc[m][c] = MFMA(a[m], pb[slot][c], pacc[m][c]);
    }
    __builtin_amdgcn_s_setprio(0);
  }

  // ---------- x2 = x + proj + bo ----------
  float* xo = x2 + (size_t)b * TT * CC;
#pragma unroll
  for (int m = 0; m < 4; ++m)
#pragma unroll
    for (int c = 0; c < 6; ++c) {
      int n = wv * 96 + c * 16 + l16;
      float bov = bo[n];
#pragma unroll
      for (int rg = 0; rg < 4; ++rg) {
        int t = m * 16 + lg * 4 + rg;
        xo[t * CC + n] = xb[t * CC + n] + pacc[m][c][rg] + bov;
      }
    }
}

// ---- kernel B v3: LN2 + MLP + residual; M=128 (one WG per BLOCK PAIR).
// 512 thr / 8 waves / 1 WG/CU; LDS = 96K sXN + 16K sH + 48K sW = 160 KB exact.
// GEMM1: wave-pair row split (wave: 64 rows x 16 chunk-cols); GEMM2: full-M
// (wave: 128 rows x 48 out-cols). Weights staged per-wave via global_load_lds
// double-buffer + counted vmcnt (R7-verified patterns).
__global__ __launch_bounds__(512, 2)
void mlp_fwd(const float* __restrict__ ln2g, const float* __restrict__ ln2b,
             const float* __restrict__ b1, const float* __restrict__ b2,
             const unsigned short* __restrict__ W1T,
             const unsigned short* __restrict__ W2T,
             float* xo) {
  __shared__ unsigned short sXN[128 * 384];  // xn2, XOR-swizzled, 96 KB
  __shared__ unsigned short sH[128 * 64];    // relu(h) 64-col chunk, swizzled, 16 KB
  __shared__ unsigned short sW[8 * 3072];    // per-wave weight dbuf (6 KB each), 48 KB

  const int bp = blockIdx.x;     // block pair
  const int tid = threadIdx.x;
  const int wv = tid >> 6;       // 0..7
  const int ln = tid & 63;
  const int l16 = ln & 15;
  const int lg = ln >> 4;
  const int g = wv >> 2;         // GEMM1 row group (0: rows 0-63, 1: 64-127)
  const int p = wv & 3;          // GEMM1 col sub-stripe (16 cols)
  float* xb = xo + (size_t)bp * 128 * CC;  // x2 rows of block pair (contiguous)
  const f32x4 Z4 = {0.f, 0.f, 0.f, 0.f};
  unsigned short* myW = sW + wv * 3072;  // 6 KB per wave

  // ---------- LN2: 8 waves x 16 rows ----------
#pragma unroll 1
  for (int r = wv * 16; r < wv * 16 + 16; ++r) {
    float v[6], s = 0.f, sq = 0.f;
#pragma unroll
    for (int j = 0; j < 6; ++j) { v[j] = xb[r * CC + ln + 64 * j]; s += v[j]; sq += v[j] * v[j]; }
#pragma unroll
    for (int off = 32; off; off >>= 1) { s += __shfl_xor(s, off); sq += __shfl_xor(sq, off); }
    float mu = s * (1.f / CC);
    float rs = rsqrtf(sq * (1.f / CC) - mu * mu + 1e-5f);
#pragma unroll
    for (int j = 0; j < 6; ++j) {
      int c = ln + 64 * j;
      sXN[r * 384 + (c ^ ((r & 7) << 3))] = f2bf((v[j] - mu) * rs * ln2g[c] + ln2b[c]);
    }
  }
  __syncthreads();

  // staging lane constants (pre-swizzled global source per m173/T2)
  const int w1r = ln >> 3;                          // + j*8 rows
  const int w1k = ((ln & 7) ^ (ln >> 3)) << 3;      // k-seg source swizzle
  const int w2r = ln >> 2;                          // + j*16 rows
  const int w2k = (((ln & 3) ^ ((ln >> 3) & 3))) << 3;
  const int rsw = (l16 & 7) << 3;                   // read-side swizzle (rows ~ l16)

  f32x4 macc[8][3];
#pragma unroll
  for (int m = 0; m < 8; ++m)
#pragma unroll
    for (int c = 0; c < 3; ++c) macc[m][c] = Z4;

#pragma unroll 1
  for (int ch = 0; ch < 24; ++ch) {
    // ============ GEMM1: hacc = xn2[g-rows] @ W1[:, ch*64+p*16 .. +16) ============
    f32x4 hacc[4];
#pragma unroll
    for (int m = 0; m < 4; ++m) hacc[m] = Z4;

    const unsigned short* w1g = W1T + (size_t)(ch * 64 + p * 16 + w1r) * CC + w1k;
    // stage slice 0 -> buf 0
#pragma unroll
    for (int j = 0; j < 2; ++j) glds16(w1g + (size_t)(j * 8) * CC, myW + j * 512);
    int cb = 0;
#pragma unroll 1
    for (int s = 0; s < 6; ++s) {
      if (s < 5) {
        const unsigned short* gsrc = w1g + (s + 1) * 64;
        unsigned short* d = myW + (cb ^ 1) * 1024;
#pragma unroll
        for (int j = 0; j < 2; ++j) glds16(gsrc + (size_t)(j * 8) * CC, d + j * 512);
        WAITVM(2);   // slice s landed (its 2 loads are oldest)
      } else {
        WAITVM(0);
      }
#pragma unroll
      for (int kk2 = 0; kk2 < 2; ++kk2) {
        bf16x8 a[4];
#pragma unroll
        for (int m = 0; m < 4; ++m)
          a[m] = ld8(&sXN[(g * 64 + m * 16 + l16) * 384 + ((s * 64 + kk2 * 32 + 8 * lg) ^ rsw)]);
        bf16x8 bb = ld8(&myW[cb * 1024 + l16 * 64 + ((kk2 * 32 + 8 * lg) ^ rsw)]);
        __builtin_amdgcn_s_setprio(1);
#pragma unroll
        for (int m = 0; m < 4; ++m) hacc[m] = MFMA(a[m], bb, hacc[m]);
        __builtin_amdgcn_s_setprio(0);
      }
      cb ^= 1;
    }
    __syncthreads();  // A: all waves done GEMM1(ch) => prior GEMM2 reads + sH reads done

    // stage W2 slice 0 early (own region free; latency hides under sH write + barrier)
    const unsigned short* w2g = W2T + (size_t)(wv * 48 + w2r) * HID + ch * 64 + w2k;
#pragma unroll
    for (int j = 0; j < 3; ++j) glds16(w2g + (size_t)(j * 16) * HID, myW + j * 512);

    // write sH = relu(hacc + b1)  (wave's 64 rows x 16 cols)
    {
      float b1v = b1[ch * 64 + p * 16 + l16];
#pragma unroll
      for (int m = 0; m < 4; ++m)
#pragma unroll
        for (int rg = 0; rg < 4; ++rg) {
          int row = g * 64 + m * 16 + lg * 4 + rg;
          int col = p * 16 + l16;
          sH[row * 64 + (col ^ ((row & 7) << 3))] = f2bf(fmaxf(hacc[m][rg] + b1v, 0.f));
        }
    }
    __syncthreads();  // B: sH visible; barrier drains vmcnt -> W2 slice0 ready

    // ============ GEMM2: macc += relu_h @ W2[ch-slice], 2 slices BK=32 ============
    cb = 0;
#pragma unroll 1
    for (int s = 0; s < 2; ++s) {
      if (s == 0) {
        // stage slice 1 -> buf 1 (slice 0 already drained by barrier B)
#pragma unroll
        for (int j = 0; j < 3; ++j) glds16(w2g + 32 + (size_t)(j * 16) * HID, myW + 1536 + j * 512);
      } else {
        WAITVM(0);
      }
      bf16x8 a[8];
#pragma unroll
      for (int m = 0; m < 8; ++m)
        a[m] = ld8(&sH[(m * 16 + l16) * 64 + ((s * 32 + 8 * lg) ^ rsw)]);
      __builtin_amdgcn_s_setprio(1);
#pragma unroll
      for (int c = 0; c < 3; ++c) {
        int rloc = c * 16 + l16;
        bf16x8 bb = ld8(&myW[cb * 1536 + rloc * 32 + ((8 * lg) ^ (((rloc >> 1) & 3) << 3))]);
#pragma unroll
        for (int m = 0; m < 8; ++m) macc[m][c] = MFMA(a[m], bb, macc[m][c]);
      }
      __builtin_amdgcn_s_setprio(0);
      cb ^= 1;
    }
  }

  // ---------- out = x2 + mlp + b2 (read-before-write, same buffer; 128 rows) ----------
#pragma unroll
  for (int m = 0; m < 8; ++m)
#pragma unroll
    for (int c = 0; c < 3; ++c) {
      int n = wv * 48 + c * 16 + l16;
      float b2v = b2[n];
#pragma unroll
      for (int rg = 0; rg < 4; ++rg) {
        int t = m * 16 + lg * 4 + rg;
        size_t idx = (size_t)t * CC + n;
        float x2v = xb[idx];
        xb[idx] = x2v + macc[m][c][rg] + b2v;
      }
    }
}

extern "C" void kernel_launch(void* const* d_in, const int* in_sizes, int n_in,
                              void* d_out, int out_size, void* d_ws, size_t ws_size,
                              hipStream_t stream) {
  const float* x    = (const float*)d_in[0];
  const float* ln1g = (const float*)d_in[1];
  const float* ln1b = (const float*)d_in[2];
  const float* Wq   = (const float*)d_in[3];
  const float* Wk   = (const float*)d_in[4];
  const float* Wv   = (const float*)d_in[5];
  const float* Wo   = (const float*)d_in[6];
  const float* bo   = (const float*)d_in[7];
  const float* ln2g = (const float*)d_in[8];
  const float* ln2b = (const float*)d_in[9];
  const float* W1   = (const float*)d_in[10];
  const float* b1   = (const float*)d_in[11];
  const float* W2   = (const float*)d_in[12];
  const float* b2   = (const float*)d_in[13];
  unsigned short* ws = (unsigned short*)d_ws;

  const size_t need = (size_t)(1152 * 384 + 384 * 384 + 1536 * 384 + 384 * 1536) * 2;
  if (ws_size < need) return;

  hipLaunchKernelGGL(prep_w, dim3(1024), dim3(256), 0, stream, Wq, Wk, Wv, Wo, W1, W2, ws);

  const unsigned short* Wqkv = ws;
  const unsigned short* WoT  = ws + 1152 * 384;
  const unsigned short* W1T  = WoT + 384 * 384;
  const unsigned short* W2T  = W1T + 1536 * 384;
  int nblk = in_sizes[0] / (TT * CC);

  hipLaunchKernelGGL(attn_fwd, dim3(nblk), dim3(256), 0, stream,
                     x, ln1g, ln1b, bo, Wqkv, WoT, (float*)d_out);
  hipLaunchKernelGGL(mlp_fwd, dim3(nblk / 2), dim3(512), 0, stream,
                     ln2g, ln2b, b1, b2, W1T, W2T, (float*)d_out);
}

// Round 9
// 462.423 us; speedup vs baseline: 1.0188x; 1.0188x over previous
//
#include <hip/hip_runtime.h>

#define TT 64
#define CC 384
#define NH 6
#define HID 1536
#define LDX 392   // attn: padded cols for 64x384 bf16 tiles
#define LDH 72    // attn head tiles (144B stride)

typedef __bf16 bf16x8 __attribute__((ext_vector_type(8)));
typedef float f32x4 __attribute__((ext_vector_type(4)));
typedef unsigned short us8 __attribute__((ext_vector_type(8)));

#define MFMA(a, b, c) __builtin_amdgcn_mfma_f32_16x16x32_bf16(a, b, c, 0, 0, 0)
#define WAITVM(N) asm volatile("s_waitcnt vmcnt(" #N ")" ::: "memory")

static __device__ __forceinline__ unsigned short f2bf(float f) {
  unsigned u = __builtin_bit_cast(unsigned, f);
  u += 0x7FFFu + ((u >> 16) & 1u);
  return (unsigned short)(u >> 16);
}
static __device__ __forceinline__ float bf2f(unsigned short h) {
  unsigned u = ((unsigned)h) << 16;
  return __builtin_bit_cast(float, u);
}
static __device__ __forceinline__ bf16x8 ld8(const unsigned short* p) {
  return __builtin_bit_cast(bf16x8, *reinterpret_cast<const us8*>(p));
}
// async global->LDS, 16B per lane; lds dest = wave-uniform base + lane*16
static __device__ __forceinline__ void glds16(const unsigned short* g, unsigned short* l) {
  __builtin_amdgcn_global_load_lds(
      (const __attribute__((address_space(1))) void*)g,
      (__attribute__((address_space(3))) void*)l, 16, 0, 0);
}

// ---- weight prep: fp32 -> bf16, transposed to [n][k] for MFMA B-frags ----
__global__ void prep_w(const float* __restrict__ Wq, const float* __restrict__ Wk,
                       const float* __restrict__ Wv, const float* __restrict__ Wo,
                       const float* __restrict__ W1, const float* __restrict__ W2,
                       unsigned short* __restrict__ ws) {
  const int T0 = 1152 * 384;            // Wqkv [h*192+j][k]
  const int T1 = T0 + 384 * 384;        // WoT  [n][k]
  const int T2 = T1 + 1536 * 384;       // W1T  [n][k]
  const int T3 = T2 + 384 * 1536;       // W2T  [n][k]
  for (int i = blockIdx.x * blockDim.x + threadIdx.x; i < T3; i += gridDim.x * blockDim.x) {
    float v;
    if (i < T0) {
      int n = i / 384, k = i % 384;
      int hh = n / 192, j = n % 192;
      const float* W = (j < 64) ? Wq : (j < 128) ? Wk : Wv;
      int d = (j < 64) ? j : (j < 128) ? j - 64 : j - 128;
      v = W[((size_t)hh * 384 + k) * 64 + d];
    } else if (i < T1) {
      int i2 = i - T0; int n = i2 / 384, k = i2 % 384;
      v = Wo[(size_t)k * 384 + n];
    } else if (i < T2) {
      int i2 = i - T1; int n = i2 / 384, k = i2 % 384;
      v = W1[(size_t)k * 1536 + n];
    } else {
      int i2 = i - T2; int n = i2 / 1536, k = i2 % 1536;
      v = W2[(size_t)k * 384 + n];
    }
    ws[i] = f2bf(v);
  }
}

// ---- kernel A: LN1 + attention + per-head proj accumulation + residual -> x2 (=d_out, fp32)
__global__ __launch_bounds__(256, 2)
void attn_fwd(const float* __restrict__ x,
              const float* __restrict__ ln1g, const float* __restrict__ ln1b,
              const float* __restrict__ bo,
              const unsigned short* __restrict__ Wqkv,
              const unsigned short* __restrict__ WoT,
              float* __restrict__ x2) {
  __shared__ unsigned short sXN[TT * LDX];       // xn1 (bf16)
  __shared__ unsigned short sHEAD[3 * TT * LDH]; // q | k (later att_h) | vT
  unsigned short* sQ = sHEAD;                    // q [t][d]; later P [t][s]
  unsigned short* sK = sHEAD + TT * LDH;         // k [s][d]; later att_h [t][d]
  unsigned short* sV = sHEAD + 2 * TT * LDH;     // vT [d][s]

  const int b = blockIdx.x;
  const int tid = threadIdx.x;
  const int wv = tid >> 6;
  const int ln = tid & 63;
  const int l16 = ln & 15;
  const int lg = ln >> 4;
  const float* xb = x + (size_t)b * TT * CC;
  const f32x4 Z4 = {0.f, 0.f, 0.f, 0.f};

  // ---------- LN1 ----------
#pragma unroll 1
  for (int r = wv * 16; r < wv * 16 + 16; ++r) {
    float v[6], s = 0.f, sq = 0.f;
#pragma unroll
    for (int j = 0; j < 6; ++j) { v[j] = xb[r * CC + ln + 64 * j]; s += v[j]; sq += v[j] * v[j]; }
#pragma unroll
    for (int off = 32; off; off >>= 1) { s += __shfl_xor(s, off); sq += __shfl_xor(sq, off); }
    float mu = s * (1.f / CC);
    float rs = rsqrtf(sq * (1.f / CC) - mu * mu + 1e-5f);
#pragma unroll
    for (int j = 0; j < 6; ++j) {
      int c = ln + 64 * j;
      sXN[r * LDX + c] = f2bf((v[j] - mu) * rs * ln1g[c] + ln1b[c]);
    }
  }
  __syncthreads();

  f32x4 pacc[4][6];
#pragma unroll
  for (int m = 0; m < 4; ++m)
#pragma unroll
    for (int c = 0; c < 6; ++c) pacc[m][c] = Z4;

  const unsigned short* prow[6];
#pragma unroll
  for (int c = 0; c < 6; ++c)
    prow[c] = WoT + (size_t)(wv * 96 + c * 16 + l16) * CC + 8 * lg;

#pragma unroll 1
  for (int h = 0; h < NH; ++h) {
    const unsigned short* wrow[3];
#pragma unroll
    for (int c = 0; c < 3; ++c)
      wrow[c] = Wqkv + (size_t)(h * 192 + wv * 48 + c * 16 + l16) * CC + 8 * lg;

    f32x4 qacc[4][3];
#pragma unroll
    for (int m = 0; m < 4; ++m)
#pragma unroll
      for (int c = 0; c < 3; ++c) qacc[m][c] = Z4;

    // depth-2 B prefetch pipeline
    bf16x8 bpre[2][3];
#pragma unroll
    for (int c = 0; c < 3; ++c) bpre[0][c] = ld8(wrow[c] + 0);
#pragma unroll
    for (int c = 0; c < 3; ++c) bpre[1][c] = ld8(wrow[c] + 32);
#pragma unroll
    for (int kk = 0; kk < CC; kk += 32) {
      const int slot = (kk >> 5) & 1;
      bf16x8 bcur[3];
#pragma unroll
      for (int c = 0; c < 3; ++c) bcur[c] = bpre[slot][c];
      if (kk + 64 < CC) {
#pragma unroll
        for (int c = 0; c < 3; ++c) bpre[slot][c] = ld8(wrow[c] + kk + 64);
      }
      bf16x8 a[4];
#pragma unroll
      for (int m = 0; m < 4; ++m)
        a[m] = ld8(&sXN[(m * 16 + l16) * LDX + kk + 8 * lg]);
      __builtin_amdgcn_s_setprio(1);
#pragma unroll
      for (int c = 0; c < 3; ++c)
#pragma unroll
        for (int m = 0; m < 4; ++m) qacc[m][c] = MFMA(a[m], bcur[c], qacc[m][c]);
      __builtin_amdgcn_s_setprio(0);
    }
    __syncthreads();  // B1
    // scatter: q [t][d], k [s][d], vT [d][s]
#pragma unroll
    for (int m = 0; m < 4; ++m)
#pragma unroll
      for (int c = 0; c < 3; ++c) {
        int n = wv * 48 + c * 16 + l16;
#pragma unroll
        for (int rg = 0; rg < 4; ++rg) {
          int t = m * 16 + lg * 4 + rg;
          unsigned short bv = f2bf(qacc[m][c][rg]);
          if (n < 64) sQ[t * LDH + n] = bv;
          else if (n < 128) sK[t * LDH + (n - 64)] = bv;
          else sV[(n - 128) * LDH + t] = bv;
        }
      }
    __syncthreads();  // B2

    // ----- S = q.kT
    f32x4 sacc[4];
#pragma unroll
    for (int c = 0; c < 4; ++c) sacc[c] = Z4;
#pragma unroll
    for (int kk = 0; kk < 64; kk += 32) {
      bf16x8 a = ld8(&sQ[(wv * 16 + l16) * LDH + kk + 8 * lg]);
#pragma unroll
      for (int c = 0; c < 4; ++c) {
        bf16x8 bb = ld8(&sK[(c * 16 + l16) * LDH + kk + 8 * lg]);
        sacc[c] = MFMA(a, bb, sacc[c]);
      }
    }
    // causal softmax
#pragma unroll
    for (int rg = 0; rg < 4; ++rg) {
      int row = wv * 16 + lg * 4 + rg;
      float e[4], mx = -1e30f;
#pragma unroll
      for (int c = 0; c < 4; ++c) {
        int col = c * 16 + l16;
        float vv = sacc[c][rg] * 0.125f;
        e[c] = (col <= row) ? vv : -1e30f;
        mx = fmaxf(mx, e[c]);
      }
#pragma unroll
      for (int off = 8; off; off >>= 1) mx = fmaxf(mx, __shfl_xor(mx, off));
      float sum = 0.f;
#pragma unroll
      for (int c = 0; c < 4; ++c) {
        int col = c * 16 + l16;
        e[c] = (col <= row) ? __expf(e[c] - mx) : 0.f;
        sum += e[c];
      }
#pragma unroll
      for (int off = 8; off; off >>= 1) sum += __shfl_xor(sum, off);
      float inv = 1.f / sum;
#pragma unroll
      for (int c = 0; c < 4; ++c)
        sQ[row * LDH + c * 16 + l16] = f2bf(e[c] * inv);
    }

    // Preload ALL Wo B-frags for this head (latency hides under PV)
    bf16x8 pb[2][6];
#pragma unroll
    for (int s2 = 0; s2 < 2; ++s2)
#pragma unroll
      for (int c = 0; c < 6; ++c)
        pb[s2][c] = ld8(prow[c] + h * 64 + 32 * s2);

    // ----- out_h = P @ V
    f32x4 oacc[4];
#pragma unroll
    for (int c = 0; c < 4; ++c) oacc[c] = Z4;
#pragma unroll
    for (int kk = 0; kk < 64; kk += 32) {
      bf16x8 a = ld8(&sQ[(wv * 16 + l16) * LDH + kk + 8 * lg]);
#pragma unroll
      for (int c = 0; c < 4; ++c) {
        bf16x8 bb = ld8(&sV[(c * 16 + l16) * LDH + kk + 8 * lg]);
        oacc[c] = MFMA(a, bb, oacc[c]);
      }
    }
    __syncthreads();  // B3
#pragma unroll
    for (int c = 0; c < 4; ++c)
#pragma unroll
      for (int rg = 0; rg < 4; ++rg) {
        int t = wv * 16 + lg * 4 + rg;
        sK[t * LDH + c * 16 + l16] = f2bf(oacc[c][rg]);
      }
    __syncthreads();  // B4

    // ----- proj accumulate (B in regs)
    __builtin_amdgcn_s_setprio(1);
#pragma unroll
    for (int kk = 0; kk < 64; kk += 32) {
      const int slot = kk >> 5;
      bf16x8 a[4];
#pragma unroll
      for (int m = 0; m < 4; ++m)
        a[m] = ld8(&sK[(m * 16 + l16) * LDH + kk + 8 * lg]);
#pragma unroll
      for (int c = 0; c < 6; ++c)
#pragma unroll
        for (int m = 0; m < 4; ++m) pacc[m][c] = MFMA(a[m], pb[slot][c], pacc[m][c]);
    }
    __builtin_amdgcn_s_setprio(0);
  }

  // ---------- x2 = x + proj + bo ----------
  float* xo = x2 + (size_t)b * TT * CC;
#pragma unroll
  for (int m = 0; m < 4; ++m)
#pragma unroll
    for (int c = 0; c < 6; ++c) {
      int n = wv * 96 + c * 16 + l16;
      float bov = bo[n];
#pragma unroll
      for (int rg = 0; rg < 4; ++rg) {
        int t = m * 16 + lg * 4 + rg;
        xo[t * CC + n] = xb[t * CC + n] + pacc[m][c][rg] + bov;
      }
    }
}

// ---- kernel B v4: LN2 + MLP + residual; M=64, chunk=128 (12 chunks).
// 512 thr / 8 waves / 1 WG/CU; LDS = 48K sXN + 16K sH + 96K sW = 160 KB exact.
// Depth-3 per-wave weight staging with counted vmcnt that never drains mid-chunk;
// next chunk's GEMM1 prologue issued during current GEMM2 (cross-phase in-flight).
__global__ __launch_bounds__(512, 2)
void mlp_fwd(const float* __restrict__ ln2g, const float* __restrict__ ln2b,
             const float* __restrict__ b1, const float* __restrict__ b2,
             const unsigned short* __restrict__ W1T,
             const unsigned short* __restrict__ W2T,
             float* xo) {
  __shared__ unsigned short sXN[TT * 384];   // xn2, XOR-swizzled, 48 KB
  __shared__ unsigned short sH[TT * 128];    // relu(h) chunk, XOR-swizzled, 16 KB
  __shared__ unsigned short sW[8 * 6144];    // per-wave staging (12 KB each), 96 KB

  const int b = blockIdx.x;
  const int tid = threadIdx.x;
  const int wv = tid >> 6;      // 0..7
  const int ln = tid & 63;
  const int l16 = ln & 15;
  const int lg = ln >> 4;
  float* xb = xo + (size_t)b * TT * CC;
  const f32x4 Z4 = {0.f, 0.f, 0.f, 0.f};
  unsigned short* myW = sW + wv * 6144;

  const int rsw = (l16 & 7) << 3;                    // read-side XOR swizzle
  const int w1r = ln >> 3;                           // W1 staging: +j*8 rows
  const int w1k = ((ln & 7) ^ (ln >> 3)) << 3;       // pre-swizzled k source
  const int w2r = ln >> 2;                           // W2 staging: +j*16 rows
  const int w2k = (((ln & 3) ^ ((ln >> 3) & 3))) << 3;

  // ---------- LN2: 8 waves x 8 rows, swizzled sXN ----------
#pragma unroll 1
  for (int r = wv * 8; r < wv * 8 + 8; ++r) {
    float v[6], s = 0.f, sq = 0.f;
#pragma unroll
    for (int j = 0; j < 6; ++j) { v[j] = xb[r * CC + ln + 64 * j]; s += v[j]; sq += v[j] * v[j]; }
#pragma unroll
    for (int off = 32; off; off >>= 1) { s += __shfl_xor(s, off); sq += __shfl_xor(sq, off); }
    float mu = s * (1.f / CC);
    float rs = rsqrtf(sq * (1.f / CC) - mu * mu + 1e-5f);
#pragma unroll
    for (int j = 0; j < 6; ++j) {
      int c = ln + 64 * j;
      sXN[r * 384 + (c ^ ((r & 7) << 3))] = f2bf((v[j] - mu) * rs * ln2g[c] + ln2b[c]);
    }
  }
  __syncthreads();   // drains LN2's x-loads: vmcnt == 0 here

// GEMM1 slice SS staging: [16 rows][64 k] = 2 glds16 -> buf (SS%3)*1024
#define G1_STAGE(P, SS) do {                                                 \
    glds16((P) + (SS) * 64, myW + ((SS) % 3) * 1024);                        \
    glds16((P) + (SS) * 64 + (size_t)8 * CC, myW + ((SS) % 3) * 1024 + 512); \
  } while (0)

// GEMM1 slice SS compute: 8 MFMA into hacc
#define G1_COMP(SS) do {                                                              \
    _Pragma("unroll")                                                                 \
    for (int kk2 = 0; kk2 < 2; ++kk2) {                                               \
      bf16x8 a_[4];                                                                   \
      _Pragma("unroll")                                                               \
      for (int m = 0; m < 4; ++m)                                                     \
        a_[m] = ld8(&sXN[(m * 16 + l16) * 384 +                                       \
                         (((SS) * 64 + kk2 * 32 + 8 * lg) ^ rsw)]);                   \
      bf16x8 bb_ = ld8(&myW[((SS) % 3) * 1024 + l16 * 64 + ((kk2 * 32 + 8 * lg) ^ rsw)]); \
      __builtin_amdgcn_s_setprio(1);                                                  \
      _Pragma("unroll")                                                               \
      for (int m = 0; m < 4; ++m) hacc[m] = MFMA(a_[m], bb_, hacc[m]);                \
      __builtin_amdgcn_s_setprio(0);                                                  \
    }                                                                                 \
  } while (0)

// GEMM2 slice SS staging: [48 rows][32 k] = 3 glds16 -> buf SS*1536
#define G2_STAGE(SS) do {                                                      \
    glds16(w2g + (SS) * 32, myW + (SS) * 1536);                                \
    glds16(w2g + (SS) * 32 + (size_t)16 * HID, myW + (SS) * 1536 + 512);       \
    glds16(w2g + (SS) * 32 + (size_t)32 * HID, myW + (SS) * 1536 + 1024);      \
  } while (0)

// GEMM2 slice SS compute: 12 MFMA into macc
#define G2_COMP(SS) do {                                                          \
    bf16x8 a_[4];                                                                 \
    _Pragma("unroll")                                                             \
    for (int m = 0; m < 4; ++m)                                                   \
      a_[m] = ld8(&sH[(m * 16 + l16) * 128 + (((SS) * 32 + 8 * lg) ^ rsw)]);      \
    __builtin_amdgcn_s_setprio(1);                                                \
    _Pragma("unroll")                                                             \
    for (int c = 0; c < 3; ++c) {                                                 \
      int rloc_ = c * 16 + l16;                                                   \
      bf16x8 bb_ = ld8(&myW[(SS) * 1536 + rloc_ * 32 +                            \
                            ((8 * lg) ^ (((rloc_ >> 1) & 3) << 3))]);             \
      _Pragma("unroll")                                                           \
      for (int m = 0; m < 4; ++m) macc[m][c] = MFMA(a_[m], bb_, macc[m][c]);      \
    }                                                                             \
    __builtin_amdgcn_s_setprio(0);                                                \
  } while (0)

  f32x4 macc[4][3];
#pragma unroll
  for (int m = 0; m < 4; ++m)
#pragma unroll
    for (int c = 0; c < 3; ++c) macc[m][c] = Z4;

  // chunk-0 GEMM1 prologue: slices 0..2 in flight (6 loads)
  const unsigned short* w1g = W1T + (size_t)(0 * 128 + wv * 16 + w1r) * CC + w1k;
  G1_STAGE(w1g, 0); G1_STAGE(w1g, 1); G1_STAGE(w1g, 2);

#pragma unroll 1
  for (int ch = 0; ch < 12; ++ch) {
    f32x4 hacc[4];
#pragma unroll
    for (int m = 0; m < 4; ++m) hacc[m] = Z4;

    // ---- GEMM1: 6 slices, depth-3, issue-after-compute ----
    WAITVM(4); G1_COMP(0); G1_STAGE(w1g, 3);
    WAITVM(4); G1_COMP(1); G1_STAGE(w1g, 4);
    WAITVM(4); G1_COMP(2); G1_STAGE(w1g, 5);
    WAITVM(4); G1_COMP(3);
    WAITVM(2); G1_COMP(4);
    WAITVM(0); G1_COMP(5);

    // issue GEMM2 slices 0,1 now; barrier A's drain absorbs their latency
    const unsigned short* w2g = W2T + (size_t)(wv * 48 + w2r) * HID + ch * 128 + w2k;
    G2_STAGE(0); G2_STAGE(1);
    float b1v = b1[ch * 128 + wv * 16 + l16];
    __syncthreads();  // A: prev GEMM2 sH reads done; drains vmcnt (g2 s0,s1 + b1 land)

    // sH = relu(hacc + b1)  (wave's 16 chunk-cols x 64 rows)
    {
      int nl = wv * 16 + l16;
#pragma unroll
      for (int m = 0; m < 4; ++m)
#pragma unroll
        for (int rg = 0; rg < 4; ++rg) {
          int t = m * 16 + lg * 4 + rg;
          sH[t * 128 + (nl ^ ((t & 7) << 3))] = f2bf(fmaxf(hacc[m][rg] + b1v, 0.f));
        }
    }
    __syncthreads();  // B: sH visible

    // ---- GEMM2: 4 slices; s2/s3 + NEXT chunk's GEMM1 prologue kept in flight ----
    int chn = (ch + 1 < 12) ? ch + 1 : 0;  // last chunk: dummy re-stage of chunk 0 (never read)
    const unsigned short* w1gn = W1T + (size_t)(chn * 128 + wv * 16 + w1r) * CC + w1k;

    /*          */ G2_COMP(0); G2_STAGE(2);
    WAITVM(3);     G2_COMP(1); G2_STAGE(3);
    WAITVM(3);     G2_COMP(2); G1_STAGE(w1gn, 0); G1_STAGE(w1gn, 1);
    WAITVM(4);     G2_COMP(3); G1_STAGE(w1gn, 2);

    w1g = w1gn;
  }

  // ---------- out = x2 + mlp + b2 (read-before-write, same buffer) ----------
#pragma unroll
  for (int m = 0; m < 4; ++m)
#pragma unroll
    for (int c = 0; c < 3; ++c) {
      int n = wv * 48 + c * 16 + l16;
      float b2v = b2[n];
#pragma unroll
      for (int rg = 0; rg < 4; ++rg) {
        int t = m * 16 + lg * 4 + rg;
        size_t idx = (size_t)t * CC + n;
        float x2v = xb[idx];
        xb[idx] = x2v + macc[m][c][rg] + b2v;
      }
    }
#undef G1_STAGE
#undef G1_COMP
#undef G2_STAGE
#undef G2_COMP
}

extern "C" void kernel_launch(void* const* d_in, const int* in_sizes, int n_in,
                              void* d_out, int out_size, void* d_ws, size_t ws_size,
                              hipStream_t stream) {
  const float* x    = (const float*)d_in[0];
  const float* ln1g = (const float*)d_in[1];
  const float* ln1b = (const float*)d_in[2];
  const float* Wq   = (const float*)d_in[3];
  const float* Wk   = (const float*)d_in[4];
  const float* Wv   = (const float*)d_in[5];
  const float* Wo   = (const float*)d_in[6];
  const float* bo   = (const float*)d_in[7];
  const float* ln2g = (const float*)d_in[8];
  const float* ln2b = (const float*)d_in[9];
  const float* W1   = (const float*)d_in[10];
  const float* b1   = (const float*)d_in[11];
  const float* W2   = (const float*)d_in[12];
  const float* b2   = (const float*)d_in[13];
  unsigned short* ws = (unsigned short*)d_ws;

  const size_t need = (size_t)(1152 * 384 + 384 * 384 + 1536 * 384 + 384 * 1536) * 2;
  if (ws_size < need) return;

  hipLaunchKernelGGL(prep_w, dim3(1024), dim3(256), 0, stream, Wq, Wk, Wv, Wo, W1, W2, ws);

  const unsigned short* Wqkv = ws;
  const unsigned short* WoT  = ws + 1152 * 384;
  const unsigned short* W1T  = WoT + 384 * 384;
  const unsigned short* W2T  = W1T + 1536 * 384;
  int nblk = in_sizes[0] / (TT * CC);

  hipLaunchKernelGGL(attn_fwd, dim3(nblk), dim3(256), 0, stream,
                     x, ln1g, ln1b, bo, Wqkv, WoT, (float*)d_out);
  hipLaunchKernelGGL(mlp_fwd, dim3(nblk), dim3(512), 0, stream,
                     ln2g, ln2b, b1, b2, W1T, W2T, (float*)d_out);
}